// Round 3
// baseline (626.766 us; speedup 1.0000x reference)
//
#include <hip/hip_runtime.h>

#define Bn  32
#define IDF 1024
#define CDF 1024
#define Qn  2304
#define Sn  256

typedef _Float16 f16;
typedef _Float16 f16x2 __attribute__((ext_vector_type(2)));
typedef _Float16 f16x4 __attribute__((ext_vector_type(4)));
typedef _Float16 f16x8 __attribute__((ext_vector_type(8)));
typedef float    f32x4 __attribute__((ext_vector_type(4)));

// split fp32 into fp16 hi + fp16 lo (x ~= hi + lo, error ~2^-23*|x|)
__device__ __forceinline__ void fsplit(float x, f16& hi, f16& lo) {
    hi = (f16)x;
    lo = (f16)(x - (float)hi);
}

// ---------------------------------------------------------------------------
// K0: split W into fp16 hi/lo (runs once, ~4 MB traffic)
// ---------------------------------------------------------------------------
__global__ __launch_bounds__(256) void k_wsplit(const float* __restrict__ W,
                                                f16* __restrict__ Wh, f16* __restrict__ Wl) {
    const int idx = (blockIdx.x * 256 + threadIdx.x) * 4;
    const float4 v = *reinterpret_cast<const float4*>(&W[idx]);
    f16x4 h4, l4;
    f16 h, l;
    fsplit(v.x, h, l); h4[0] = h; l4[0] = l;
    fsplit(v.y, h, l); h4[1] = h; l4[1] = l;
    fsplit(v.z, h, l); h4[2] = h; l4[2] = l;
    fsplit(v.w, h, l); h4[3] = h; l4[3] = l;
    *reinterpret_cast<f16x4*>(&Wh[idx]) = h4;
    *reinterpret_cast<f16x4*>(&Wl[idx]) = l4;
}

// ---------------------------------------------------------------------------
// K1: srcT[b][i][s] = sum_c W[i][c] * ctx[b][c][s]  -- 3-term split-fp16 MFMA
// W fragments read DIRECT from global (L2-hot, k-contig); ctx split+transposed
// into double-buffered LDS (80B rows, conflict-free), 1 barrier/iter.
// grid (Sn/128, IDF/128, Bn), block 256 (4 waves 2x2), tile 128i x 128s
// ---------------------------------------------------------------------------
__global__ __launch_bounds__(256) void k_srcT(const f16* __restrict__ Wh,
                                              const f16* __restrict__ Wl,
                                              const float* __restrict__ ctx,
                                              f16* __restrict__ si_h, f16* __restrict__ si_l,
                                              f16* __restrict__ is_h, f16* __restrict__ is_l) {
    // LDS: ctx dbuf [2] x { Ch [128 s][40 f16] (10240) + Cl (10240) } = 40960
    __shared__ alignas(16) char smem[40960];
    const int tid = threadIdx.x;
    const int w = tid >> 6, lane = tid & 63, g = lane >> 4, l15 = lane & 15;
    const int wi = w >> 1, wq = w & 1;

    // bijective XCD swizzle over 512 blocks
    const int lin = (blockIdx.z * 8 + blockIdx.y) * 2 + blockIdx.x;
    const int swz = (lin & 7) * 64 + (lin >> 3);
    const int b = swz >> 4, rr = swz & 15;
    const int i0 = (rr >> 1) * 128, s0 = (rr & 1) * 128;

    const float* Cp = ctx + (size_t)b * CDF * Sn + s0;
    const int sl = tid & 127, ch = tid >> 7;     // ctx staging: column s, c-chunk

    // per-lane W bases (fragment rows: i = i0 + wi*64 + mf*16 + l15)
    const f16* WhL = Wh + (size_t)(i0 + wi * 64 + l15) * CDF + g * 8;
    const f16* WlL = Wl + (size_t)(i0 + wi * 64 + l15) * CDF + g * 8;

    f32x4 acc[4][4];
    {
        f32x4 z = {0.f, 0.f, 0.f, 0.f};
        #pragma unroll
        for (int mf = 0; mf < 4; ++mf)
            #pragma unroll
            for (int nf = 0; nf < 4; ++nf)
                acc[mf][nf] = z;
    }

    // ---- prologue: stage ctx tile kk=0 into buf0 ----
    {
        float cv[16];
        #pragma unroll
        for (int j = 0; j < 16; ++j)
            cv[j] = Cp[(size_t)(ch * 16 + j) * Sn + sl];
        f16x8 h0, h1, l0, l1;
        #pragma unroll
        for (int j = 0; j < 8; ++j) { f16 h, l; fsplit(cv[j], h, l); h0[j] = h; l0[j] = l; }
        #pragma unroll
        for (int j = 0; j < 8; ++j) { f16 h, l; fsplit(cv[8 + j], h, l); h1[j] = h; l1[j] = l; }
        char* cb = smem + sl * 80 + ch * 32;
        *reinterpret_cast<f16x8*>(cb)              = h0;
        *reinterpret_cast<f16x8*>(cb + 16)         = h1;
        *reinterpret_cast<f16x8*>(cb + 10240)      = l0;
        *reinterpret_cast<f16x8*>(cb + 10240 + 16) = l1;
    }
    __syncthreads();

    for (int t = 0; t < 32; ++t) {
        const int kk = t * 32;
        // ---- W fragments: direct global (issued first) ----
        f16x8 fwh[4], fwl[4];
        #pragma unroll
        for (int mf = 0; mf < 4; ++mf) {
            fwh[mf] = *reinterpret_cast<const f16x8*>(WhL + mf * 16 * CDF + kk);
            fwl[mf] = *reinterpret_cast<const f16x8*>(WlL + mf * 16 * CDF + kk);
        }
        // ---- prefetch next ctx tile into regs (in flight under MFMA) ----
        float cv[16];
        if (t < 31) {
            #pragma unroll
            for (int j = 0; j < 16; ++j)
                cv[j] = Cp[(size_t)(kk + 32 + ch * 16 + j) * Sn + sl];
        }
        // ---- ctx fragments from LDS buf[t&1] ----
        const char* cbuf = smem + (t & 1) * 20480;
        f16x8 fch[4], fcl[4];
        #pragma unroll
        for (int nf = 0; nf < 4; ++nf) {
            const int srow = wq * 64 + nf * 16 + l15;
            fch[nf] = *reinterpret_cast<const f16x8*>(cbuf + srow * 80 + g * 16);
            fcl[nf] = *reinterpret_cast<const f16x8*>(cbuf + 10240 + srow * 80 + g * 16);
        }
        // ---- MFMA (3-term) ----
        #pragma unroll
        for (int nf = 0; nf < 4; ++nf)
            #pragma unroll
            for (int mf = 0; mf < 4; ++mf) {
                acc[mf][nf] = __builtin_amdgcn_mfma_f32_16x16x32_f16(fwh[mf], fch[nf], acc[mf][nf], 0, 0, 0);
                acc[mf][nf] = __builtin_amdgcn_mfma_f32_16x16x32_f16(fwh[mf], fcl[nf], acc[mf][nf], 0, 0, 0);
                acc[mf][nf] = __builtin_amdgcn_mfma_f32_16x16x32_f16(fwl[mf], fch[nf], acc[mf][nf], 0, 0, 0);
            }
        // ---- split+write next tile into other buffer ----
        if (t < 31) {
            f16x8 h0, h1, l0, l1;
            #pragma unroll
            for (int j = 0; j < 8; ++j) { f16 h, l; fsplit(cv[j], h, l); h0[j] = h; l0[j] = l; }
            #pragma unroll
            for (int j = 0; j < 8; ++j) { f16 h, l; fsplit(cv[8 + j], h, l); h1[j] = h; l1[j] = l; }
            char* cb = smem + ((t + 1) & 1) * 20480 + sl * 80 + ch * 32;
            *reinterpret_cast<f16x8*>(cb)              = h0;
            *reinterpret_cast<f16x8*>(cb + 16)         = h1;
            *reinterpret_cast<f16x8*>(cb + 10240)      = l0;
            *reinterpret_cast<f16x8*>(cb + 10240 + 16) = l1;
        }
        __syncthreads();
    }

    // ---- epilogue: split once, store both layouts ----
    #pragma unroll
    for (int mf = 0; mf < 4; ++mf)
        #pragma unroll
        for (int nf = 0; nf < 4; ++nf) {
            f16x4 h4, l4;
            #pragma unroll
            for (int r = 0; r < 4; ++r) { f16 h, l; fsplit(acc[mf][nf][r], h, l); h4[r] = h; l4[r] = l; }
            const int s  = s0 + wq * 64 + nf * 16 + l15;
            const int ib = i0 + wi * 64 + mf * 16 + g * 4;
            const size_t so = ((size_t)b * Sn + s) * IDF + ib;
            *reinterpret_cast<f16x4*>(&si_h[so]) = h4;
            *reinterpret_cast<f16x4*>(&si_l[so]) = l4;
            #pragma unroll
            for (int r = 0; r < 4; ++r) {
                const size_t io = ((size_t)b * IDF + ib + r) * Sn + s;
                is_h[io] = h4[r];
                is_l[io] = l4[r];
            }
        }
}

// ---------------------------------------------------------------------------
// K2: logits via 3-term split-fp16 MFMA + fused masked softmax
// B (srcT) fragments read DIRECT from global (L2-hot, zero bank conflicts);
// A (inp) split+transposed into double-buffered LDS, 1 barrier/iter.
// grid (Qn/64, Bn), block 256 (4 waves 1x4), tile 64q x 256s
// ---------------------------------------------------------------------------
__global__ __launch_bounds__(256) void k_attn(const float* __restrict__ inp,
                                              const f16* __restrict__ si_h,
                                              const f16* __restrict__ si_l,
                                              const int* __restrict__ mask,
                                              float* __restrict__ out1,
                                              f16* __restrict__ Ph) {
    // LDS: A dbuf [2] x { Ah [64][40 f16] (5120) + Al (5120) } = 20480
    //      epilogue union: Pl f32 [128][68] (34816) + redm (1024) + reds (1024)
    __shared__ alignas(16) char smem[36864];
    const int tid = threadIdx.x;
    const int w = tid >> 6, lane = tid & 63, g = lane >> 4, l15 = lane & 15;

    const int lin = blockIdx.y * 36 + blockIdx.x;
    const int swz = (lin & 7) * 144 + (lin >> 3);
    const int b = swz / 36, qt = swz - b * 36;
    const int q0 = qt * 64;

    const float* Ap = inp + (size_t)b * IDF * Qn + q0;
    // per-lane B bases (fragment rows: s = w*64 + nf*16 + l15)
    const f16* BhL = si_h + (size_t)b * Sn * IDF + (size_t)(w * 64 + l15) * IDF + g * 8;
    const f16* BlL = si_l + (size_t)b * Sn * IDF + (size_t)(w * 64 + l15) * IDF + g * 8;

    f32x4 acc[4][4];
    {
        f32x4 z = {0.f, 0.f, 0.f, 0.f};
        #pragma unroll
        for (int mf = 0; mf < 4; ++mf)
            #pragma unroll
            for (int nf = 0; nf < 4; ++nf)
                acc[mf][nf] = z;
    }

    // ---- prologue: stage A tile kk=0 into buf0 ----
    {
        float av[8];
        #pragma unroll
        for (int j = 0; j < 8; ++j)
            av[j] = Ap[(size_t)(w * 8 + j) * Qn + lane];
        f16x8 ah, al;
        #pragma unroll
        for (int j = 0; j < 8; ++j) { f16 h, lo; fsplit(av[j], h, lo); ah[j] = h; al[j] = lo; }
        *reinterpret_cast<f16x8*>(smem + lane * 80 + w * 16) = ah;
        *reinterpret_cast<f16x8*>(smem + 5120 + lane * 80 + w * 16) = al;
    }
    __syncthreads();

    for (int t = 0; t < 32; ++t) {
        const int kk = t * 32;
        // ---- B fragments: direct global (issued first so vmcnt wait leaves prefetch in flight) ----
        f16x8 fbh[4], fbl[4];
        #pragma unroll
        for (int nf = 0; nf < 4; ++nf) {
            fbh[nf] = *reinterpret_cast<const f16x8*>(BhL + nf * 16 * IDF + kk);
            fbl[nf] = *reinterpret_cast<const f16x8*>(BlL + nf * 16 * IDF + kk);
        }
        // ---- prefetch next A tile ----
        float av[8];
        if (t < 31) {
            #pragma unroll
            for (int j = 0; j < 8; ++j)
                av[j] = Ap[(size_t)(kk + 32 + w * 8 + j) * Qn + lane];
        }
        // ---- A fragments from LDS buf[t&1] ----
        const char* ab = smem + (t & 1) * 10240;
        f16x8 fah[4], fal[4];
        #pragma unroll
        for (int mf = 0; mf < 4; ++mf) {
            fah[mf] = *reinterpret_cast<const f16x8*>(ab + (mf * 16 + l15) * 80 + g * 16);
            fal[mf] = *reinterpret_cast<const f16x8*>(ab + 5120 + (mf * 16 + l15) * 80 + g * 16);
        }
        // ---- MFMA (3-term) ----
        #pragma unroll
        for (int nf = 0; nf < 4; ++nf)
            #pragma unroll
            for (int mf = 0; mf < 4; ++mf) {
                acc[mf][nf] = __builtin_amdgcn_mfma_f32_16x16x32_f16(fah[mf], fbh[nf], acc[mf][nf], 0, 0, 0);
                acc[mf][nf] = __builtin_amdgcn_mfma_f32_16x16x32_f16(fah[mf], fbl[nf], acc[mf][nf], 0, 0, 0);
                acc[mf][nf] = __builtin_amdgcn_mfma_f32_16x16x32_f16(fal[mf], fbh[nf], acc[mf][nf], 0, 0, 0);
            }
        // ---- split+write next A into other buffer ----
        if (t < 31) {
            f16x8 ah, al;
            #pragma unroll
            for (int j = 0; j < 8; ++j) { f16 h, lo; fsplit(av[j], h, lo); ah[j] = h; al[j] = lo; }
            char* wb = smem + ((t + 1) & 1) * 10240;
            *reinterpret_cast<f16x8*>(wb + lane * 80 + w * 16) = ah;
            *reinterpret_cast<f16x8*>(wb + 5120 + lane * 80 + w * 16) = al;
        }
        __syncthreads();
    }

    // ---- masked softmax over s (unchanged) ----
    int mv[2][4][4];
    #pragma unroll
    for (int h2 = 0; h2 < 2; ++h2)
        #pragma unroll
        for (int r = 0; r < 4; ++r)
            #pragma unroll
            for (int nf = 0; nf < 4; ++nf)
                mv[h2][r][nf] = mask[(h2 * 16 + g * 4 + r) * Sn + w * 64 + nf * 16 + l15];

    float* redm = reinterpret_cast<float*>(smem + 34816);
    float* reds = reinterpret_cast<float*>(smem + 35840);

    float mx[4][4], sm[4][4];
    #pragma unroll
    for (int mf = 0; mf < 4; ++mf)
        #pragma unroll
        for (int r = 0; r < 4; ++r) {
            float m = -3.0e38f;
            #pragma unroll
            for (int nf = 0; nf < 4; ++nf)
                if (!mv[mf & 1][r][nf]) m = fmaxf(m, acc[mf][nf][r]);
            m = fmaxf(m, __shfl_xor(m, 1, 64));
            m = fmaxf(m, __shfl_xor(m, 2, 64));
            m = fmaxf(m, __shfl_xor(m, 4, 64));
            m = fmaxf(m, __shfl_xor(m, 8, 64));
            mx[mf][r] = m;
        }
    if (l15 == 0) {
        #pragma unroll
        for (int mf = 0; mf < 4; ++mf)
            #pragma unroll
            for (int r = 0; r < 4; ++r)
                redm[w * 64 + mf * 16 + g * 4 + r] = mx[mf][r];
    }
    __syncthreads();
    #pragma unroll
    for (int mf = 0; mf < 4; ++mf)
        #pragma unroll
        for (int r = 0; r < 4; ++r) {
            const int q = mf * 16 + g * 4 + r;
            const float gm = fmaxf(fmaxf(redm[q], redm[64 + q]), fmaxf(redm[128 + q], redm[192 + q]));
            float ssum = 0.f;
            #pragma unroll
            for (int nf = 0; nf < 4; ++nf) {
                const float p = mv[mf & 1][r][nf] ? 0.f : __expf(acc[mf][nf][r] - gm);
                acc[mf][nf][r] = p;
                ssum += p;
            }
            ssum += __shfl_xor(ssum, 1, 64);
            ssum += __shfl_xor(ssum, 2, 64);
            ssum += __shfl_xor(ssum, 4, 64);
            ssum += __shfl_xor(ssum, 8, 64);
            sm[mf][r] = ssum;
        }
    if (l15 == 0) {
        #pragma unroll
        for (int mf = 0; mf < 4; ++mf)
            #pragma unroll
            for (int r = 0; r < 4; ++r)
                reds[w * 64 + mf * 16 + g * 4 + r] = sm[mf][r];
    }
    __syncthreads();
    #pragma unroll
    for (int mf = 0; mf < 4; ++mf)
        #pragma unroll
        for (int r = 0; r < 4; ++r) {
            const int q = mf * 16 + g * 4 + r;
            const float inv = 1.0f / (reds[q] + reds[64 + q] + reds[128 + q] + reds[192 + q]);
            #pragma unroll
            for (int nf = 0; nf < 4; ++nf)
                acc[mf][nf][r] *= inv;
        }

    // ---- outputs: out1 (P^T fp32) + Ph (P fp16 [q][s]) via LDS, 2 s-halves ----
    float* Pl = reinterpret_cast<float*>(smem);
    float* O1 = out1 + (size_t)b * Sn * Qn + q0;
    f16* PhB = Ph + ((size_t)b * Qn + q0) * Sn;
    #pragma unroll
    for (int hf = 0; hf < 2; ++hf) {
        __syncthreads();
        if ((w >> 1) == hf) {
            #pragma unroll
            for (int mf = 0; mf < 4; ++mf)
                #pragma unroll
                for (int nf = 0; nf < 4; ++nf)
                    *reinterpret_cast<f32x4*>(
                        &Pl[((w & 1) * 64 + nf * 16 + l15) * 68 + mf * 16 + g * 4]) = acc[mf][nf];
        }
        __syncthreads();
        #pragma unroll
        for (int j = 0; j < 8; ++j) {
            const int sr = (tid >> 4) + j * 16;
            const int u  = (tid & 15) * 4;
            const f32x4 v = *reinterpret_cast<const f32x4*>(&Pl[sr * 68 + u]);
            *reinterpret_cast<f32x4*>(&O1[(size_t)(hf * 128 + sr) * Qn + u]) = v;
        }
        #pragma unroll
        for (int j = 0; j < 16; ++j) {
            const int colU = l15 + 16 * (j & 3);
            const int q    = (w * 4 + g) + 16 * (j >> 2);
            const float p0 = Pl[(2 * colU) * 68 + q];
            const float p1 = Pl[(2 * colU + 1) * 68 + q];
            f16x2 hh; hh[0] = (f16)p0; hh[1] = (f16)p1;
            *reinterpret_cast<f16x2*>(&PhB[(size_t)q * Sn + hf * 128 + 2 * colU]) = hh;
        }
    }
}

// ---------------------------------------------------------------------------
// K3: out0[b][i][q] = sum_s srcT[b][i][s] * P[b][q][s]   (2-term split MFMA)
// NO LDS, NO barriers: both operands k-contiguous fp16, fragments read
// direct from global (L2-hot). block 256 (4 waves 2x2), tile 128i x 128q
// ---------------------------------------------------------------------------
__global__ __launch_bounds__(256) void k_wc(const f16* __restrict__ is_h,
                                            const f16* __restrict__ is_l,
                                            const f16* __restrict__ Ph,
                                            float* __restrict__ out0) {
    const int tid = threadIdx.x;
    const int w = tid >> 6, lane = tid & 63, g = lane >> 4, l15 = lane & 15;
    const int wi = w >> 1, wq = w & 1;

    const int lin = (blockIdx.z * 8 + blockIdx.y) * 18 + blockIdx.x;
    const int swz = (lin & 7) * 576 + (lin >> 3);
    const int b = swz / 144;
    const int rr = swz - b * 144;
    const int it = rr / 18, qt = rr - it * 18;
    const int i0 = it * 128, q0 = qt * 128;

    // per-lane bases (fragment rows: i = i0+wi*64+mf*16+l15, q = q0+wq*64+nf*16+l15)
    const f16* AhL = is_h + ((size_t)b * IDF + i0 + wi * 64 + l15) * Sn + g * 8;
    const f16* AlL = is_l + ((size_t)b * IDF + i0 + wi * 64 + l15) * Sn + g * 8;
    const f16* BL  = Ph  + ((size_t)b * Qn + q0 + wq * 64 + l15) * Sn + g * 8;

    f32x4 acc[4][4];
    {
        f32x4 z = {0.f, 0.f, 0.f, 0.f};
        #pragma unroll
        for (int mf = 0; mf < 4; ++mf)
            #pragma unroll
            for (int nf = 0; nf < 4; ++nf)
                acc[mf][nf] = z;
    }

    #pragma unroll 2
    for (int kk = 0; kk < Sn; kk += 32) {
        f16x8 fah[4], fal[4], fbh[4];
        #pragma unroll
        for (int mf = 0; mf < 4; ++mf) {
            fah[mf] = *reinterpret_cast<const f16x8*>(AhL + mf * 16 * Sn + kk);
            fal[mf] = *reinterpret_cast<const f16x8*>(AlL + mf * 16 * Sn + kk);
        }
        #pragma unroll
        for (int nf = 0; nf < 4; ++nf)
            fbh[nf] = *reinterpret_cast<const f16x8*>(BL + nf * 16 * Sn + kk);
        #pragma unroll
        for (int nf = 0; nf < 4; ++nf)
            #pragma unroll
            for (int mf = 0; mf < 4; ++mf) {
                acc[mf][nf] = __builtin_amdgcn_mfma_f32_16x16x32_f16(fah[mf], fbh[nf], acc[mf][nf], 0, 0, 0);
                acc[mf][nf] = __builtin_amdgcn_mfma_f32_16x16x32_f16(fal[mf], fbh[nf], acc[mf][nf], 0, 0, 0);
            }
    }
    float* O = out0 + ((size_t)b * IDF + i0 + wi * 64) * Qn + q0 + wq * 64;
    #pragma unroll
    for (int mf = 0; mf < 4; ++mf)
        #pragma unroll
        for (int nf = 0; nf < 4; ++nf)
            #pragma unroll
            for (int r = 0; r < 4; ++r)
                O[(size_t)(mf * 16 + g * 4 + r) * Qn + nf * 16 + l15] = acc[mf][nf][r];
}

extern "C" void kernel_launch(void* const* d_in, const int* in_sizes, int n_in,
                              void* d_out, int out_size, void* d_ws, size_t ws_size,
                              hipStream_t stream) {
    const float* inp  = (const float*)d_in[0];   // [B, IDF, 48, 48]
    const float* ctx  = (const float*)d_in[1];   // [B, CDF, S]
    const int*   mask = (const int*)  d_in[2];   // [B, S]
    const float* W    = (const float*)d_in[3];   // [IDF, CDF]
    float* out0 = (float*)d_out;                             // weightedContext
    float* out1 = out0 + (size_t)Bn * IDF * Qn;              // attn_out = P^T

    char* ws = (char*)d_ws;
    const size_t SZ = (size_t)Bn * Sn * IDF * sizeof(f16);   // 16 MiB
    f16* si_h = (f16*)(ws);
    f16* si_l = (f16*)(ws + SZ);
    f16* is_h = (f16*)(ws + 2 * SZ);
    f16* is_l = (f16*)(ws + 3 * SZ);
    f16* Ph   = (f16*)(ws + 4 * SZ);                         // [B][Q][S] fp16
    // W hi/lo alias the Ph region (dead until k_attn; k_srcT completes first)
    f16* Wh   = (f16*)(ws + 4 * SZ);
    f16* Wl   = Wh + (size_t)IDF * CDF;

    hipLaunchKernelGGL(k_wsplit, dim3(IDF * CDF / 1024), dim3(256), 0, stream, W, Wh, Wl);
    hipLaunchKernelGGL(k_srcT, dim3(Sn / 128, IDF / 128, Bn), dim3(256), 0, stream,
                       Wh, Wl, ctx, si_h, si_l, is_h, is_l);
    hipLaunchKernelGGL(k_attn, dim3(Qn / 64, Bn), dim3(256), 0, stream,
                       inp, si_h, si_l, mask, out1, Ph);
    hipLaunchKernelGGL(k_wc, dim3(Qn / 128, IDF / 128, Bn), dim3(256), 0, stream,
                       is_h, is_l, Ph, out0);
}

// Round 4
// 460.016 us; speedup vs baseline: 1.3625x; 1.3625x over previous
//
#include <hip/hip_runtime.h>

#define Bn  32
#define IDF 1024
#define CDF 1024
#define Qn  2304
#define Sn  256

typedef _Float16 f16;
typedef _Float16 f16x2 __attribute__((ext_vector_type(2)));
typedef _Float16 f16x4 __attribute__((ext_vector_type(4)));
typedef _Float16 f16x8 __attribute__((ext_vector_type(8)));
typedef float    f32x4 __attribute__((ext_vector_type(4)));

// async global->LDS, 16B per lane; dest = wave-uniform base + lane*16
__device__ __forceinline__ void gll16(const void* g, void* l) {
    __builtin_amdgcn_global_load_lds((const __attribute__((address_space(1))) void*)g,
                                     (__attribute__((address_space(3))) void*)l, 16, 0, 0);
}

// split fp32 into fp16 hi + fp16 lo (x ~= hi + lo, error ~2^-23*|x|)
__device__ __forceinline__ void fsplit(float x, f16& hi, f16& lo) {
    hi = (f16)x;
    lo = (f16)(x - (float)hi);
}

// ---------------------------------------------------------------------------
// K0: split W into fp16 hi/lo (runs once, ~4 MB traffic)
// ---------------------------------------------------------------------------
__global__ __launch_bounds__(256) void k_wsplit(const float* __restrict__ W,
                                                f16* __restrict__ Wh, f16* __restrict__ Wl) {
    const int idx = (blockIdx.x * 256 + threadIdx.x) * 4;
    const float4 v = *reinterpret_cast<const float4*>(&W[idx]);
    f16x4 h4, l4;
    f16 h, l;
    fsplit(v.x, h, l); h4[0] = h; l4[0] = l;
    fsplit(v.y, h, l); h4[1] = h; l4[1] = l;
    fsplit(v.z, h, l); h4[2] = h; l4[2] = l;
    fsplit(v.w, h, l); h4[3] = h; l4[3] = l;
    *reinterpret_cast<f16x4*>(&Wh[idx]) = h4;
    *reinterpret_cast<f16x4*>(&Wl[idx]) = l4;
}

// ---------------------------------------------------------------------------
// K1: srcT[b][i][s] = sum_c W[i][c] * ctx[b][c][s]  -- 3-term split-fp16 MFMA
// W tiles staged via global_load_lds with XOR-swizzled SOURCE (rule #21):
//   LDS[row][c] = global[row][c ^ ((row>>1)&3)]; read applies same XOR.
// ctx tile: fp32 loaded coalesced, split+transposed to LDS 80B rows (clean).
// grid (Sn/128, IDF/128, Bn), block 256 (4 waves 2x2), tile 128i x 128s
// ---------------------------------------------------------------------------
__global__ __launch_bounds__(256) void k_srcT(const f16* __restrict__ Wh,
                                              const f16* __restrict__ Wl,
                                              const float* __restrict__ ctx,
                                              f16* __restrict__ si_h, f16* __restrict__ si_l,
                                              f16* __restrict__ is_h, f16* __restrict__ is_l) {
    // LDS map: Ah [128][32 f16] @0 (8192), Al @8192 (8192)
    //          Ch [128 s][40 f16 = 80B] @16384 (10240), Cl @26624 (10240) = 36864 total
    __shared__ alignas(16) char smem[36864];
    const int tid = threadIdx.x;
    const int w = tid >> 6, lane = tid & 63, g = lane >> 4, l15 = lane & 15;
    const int wi = w >> 1, wq = w & 1;

    // bijective XCD swizzle over 512 blocks
    const int lin = (blockIdx.z * 8 + blockIdx.y) * 2 + blockIdx.x;
    const int swz = (lin & 7) * 64 + (lin >> 3);
    const int b = swz >> 4, rr = swz & 15;
    const int i0 = (rr >> 1) * 128, s0 = (rr & 1) * 128;

    const float* Cp = ctx + (size_t)b * CDF * Sn + s0;
    const int sl = tid & 127, ch = tid >> 7;     // ctx staging: column s, c-chunk
    const int rxor = ((l15 >> 1) & 3) << 4;      // read-side chunk XOR (bytes)

    f32x4 acc[4][4];
    {
        f32x4 z = {0.f, 0.f, 0.f, 0.f};
        #pragma unroll
        for (int mf = 0; mf < 4; ++mf)
            #pragma unroll
            for (int nf = 0; nf < 4; ++nf)
                acc[mf][nf] = z;
    }

    for (int kk = 0; kk < CDF; kk += 32) {
        // ---- A staging: Wh/Wl [128 i][32 c], source-swizzled global_load_lds ----
        #pragma unroll
        for (int t2 = 0; t2 < 2; ++t2) {
            const int byt = (w * 2 + t2) * 1024 + lane * 16;
            const int rw = byt >> 6;
            const int co = ((((byt >> 4) & 3) ^ ((rw >> 1) & 3)) << 3);   // f16 units
            const size_t go = (size_t)(i0 + rw) * CDF + kk + co;
            gll16(Wh + go, smem + (w * 2 + t2) * 1024);
            gll16(Wl + go, smem + 8192 + (w * 2 + t2) * 1024);
        }
        // ---- B staging: ctx [32 c][128 s] fp32 -> LDS [s][c] hi/lo (80B rows) ----
        float cv[16];
        #pragma unroll
        for (int j = 0; j < 16; ++j)
            cv[j] = Cp[(size_t)(kk + ch * 16 + j) * Sn + sl];
        f16x8 h0, h1, l0, l1;
        #pragma unroll
        for (int j = 0; j < 8; ++j) { f16 h, l; fsplit(cv[j], h, l); h0[j] = h; l0[j] = l; }
        #pragma unroll
        for (int j = 0; j < 8; ++j) { f16 h, l; fsplit(cv[8 + j], h, l); h1[j] = h; l1[j] = l; }
        char* cb = smem + 16384 + sl * 80 + ch * 32;
        *reinterpret_cast<f16x8*>(cb)              = h0;
        *reinterpret_cast<f16x8*>(cb + 16)         = h1;
        *reinterpret_cast<f16x8*>(cb + 10240)      = l0;
        *reinterpret_cast<f16x8*>(cb + 10240 + 16) = l1;
        __syncthreads();

        // ---- fragments + MFMA (3-term) ----
        f16x8 fah[4], fal[4];
        #pragma unroll
        for (int mf = 0; mf < 4; ++mf) {
            const int row = wi * 64 + mf * 16 + l15;
            fah[mf] = *reinterpret_cast<const f16x8*>(smem + row * 64 + ((g * 16) ^ rxor));
            fal[mf] = *reinterpret_cast<const f16x8*>(smem + 8192 + row * 64 + ((g * 16) ^ rxor));
        }
        #pragma unroll
        for (int nf = 0; nf < 4; ++nf) {
            const int srow = wq * 64 + nf * 16 + l15;
            const f16x8 fbh = *reinterpret_cast<const f16x8*>(smem + 16384 + srow * 80 + g * 16);
            const f16x8 fbl = *reinterpret_cast<const f16x8*>(smem + 26624 + srow * 80 + g * 16);
            #pragma unroll
            for (int mf = 0; mf < 4; ++mf) {
                acc[mf][nf] = __builtin_amdgcn_mfma_f32_16x16x32_f16(fah[mf], fbh, acc[mf][nf], 0, 0, 0);
                acc[mf][nf] = __builtin_amdgcn_mfma_f32_16x16x32_f16(fah[mf], fbl, acc[mf][nf], 0, 0, 0);
                acc[mf][nf] = __builtin_amdgcn_mfma_f32_16x16x32_f16(fal[mf], fbh, acc[mf][nf], 0, 0, 0);
            }
        }
        __syncthreads();
    }

    // ---- epilogue: split once, store both layouts ----
    #pragma unroll
    for (int mf = 0; mf < 4; ++mf)
        #pragma unroll
        for (int nf = 0; nf < 4; ++nf) {
            f16x4 h4, l4;
            #pragma unroll
            for (int r = 0; r < 4; ++r) { f16 h, l; fsplit(acc[mf][nf][r], h, l); h4[r] = h; l4[r] = l; }
            const int s  = s0 + wq * 64 + nf * 16 + l15;
            const int ib = i0 + wi * 64 + mf * 16 + g * 4;
            const size_t so = ((size_t)b * Sn + s) * IDF + ib;
            *reinterpret_cast<f16x4*>(&si_h[so]) = h4;
            *reinterpret_cast<f16x4*>(&si_l[so]) = l4;
            #pragma unroll
            for (int r = 0; r < 4; ++r) {
                const size_t io = ((size_t)b * IDF + ib + r) * Sn + s;
                is_h[io] = h4[r];
                is_l[io] = l4[r];
            }
        }
}

// ---------------------------------------------------------------------------
// K2: logits via 3-term split-fp16 MFMA + fused masked softmax
// B tiles via source-swizzled global_load_lds (conflict-free reads);
// A (inp) split+transposed to LDS 80B rows (clean).
// grid (Qn/64, Bn), block 256 (4 waves 1x4), tile 64q x 256s
// ---------------------------------------------------------------------------
__global__ __launch_bounds__(256) void k_attn(const float* __restrict__ inp,
                                              const f16* __restrict__ si_h,
                                              const f16* __restrict__ si_l,
                                              const int* __restrict__ mask,
                                              float* __restrict__ out1,
                                              f16* __restrict__ Ph) {
    // LDS: Ah [64][40 f16] @0 (5120), Al @5120 (5120)
    //      Bh [256][32 f16] @10240 (16384), Bl @26624 (16384) = 43008
    //      union after K-loop: Pl f32 [128][68] @0 (34816), redm @34816, reds @35840
    __shared__ alignas(16) char smem[43008];
    const int tid = threadIdx.x;
    const int w = tid >> 6, lane = tid & 63, g = lane >> 4, l15 = lane & 15;
    const int rxor = ((l15 >> 1) & 3) << 4;

    const int lin = blockIdx.y * 36 + blockIdx.x;
    const int swz = (lin & 7) * 144 + (lin >> 3);
    const int b = swz / 36, qt = swz - b * 36;
    const int q0 = qt * 64;

    const float* Ap = inp + (size_t)b * IDF * Qn + q0;
    const f16* BhG = si_h + (size_t)b * Sn * IDF;
    const f16* BlG = si_l + (size_t)b * Sn * IDF;

    f32x4 acc[4][4];
    {
        f32x4 z = {0.f, 0.f, 0.f, 0.f};
        #pragma unroll
        for (int mf = 0; mf < 4; ++mf)
            #pragma unroll
            for (int nf = 0; nf < 4; ++nf)
                acc[mf][nf] = z;
    }

    for (int kk = 0; kk < IDF; kk += 32) {
        // ---- B staging: source-swizzled global_load_lds ----
        #pragma unroll
        for (int it = 0; it < 4; ++it) {
            const int byt = w * 4096 + it * 1024 + lane * 16;
            const int s = byt >> 6;
            const int ko = ((((byt >> 4) & 3) ^ ((s >> 1) & 3)) << 3);    // f16 units
            const size_t go = (size_t)s * IDF + kk + ko;
            gll16(BhG + go, smem + 10240 + w * 4096 + it * 1024);
            gll16(BlG + go, smem + 26624 + w * 4096 + it * 1024);
        }
        // ---- A staging: load fp32 coalesced, split, transpose-write ----
        float av[8];
        #pragma unroll
        for (int j = 0; j < 8; ++j)
            av[j] = Ap[(size_t)(kk + w * 8 + j) * Qn + lane];
        f16x8 ah, al;
        #pragma unroll
        for (int j = 0; j < 8; ++j) { f16 h, lo; fsplit(av[j], h, lo); ah[j] = h; al[j] = lo; }
        *reinterpret_cast<f16x8*>(smem + lane * 80 + w * 16) = ah;
        *reinterpret_cast<f16x8*>(smem + 5120 + lane * 80 + w * 16) = al;
        __syncthreads();

        // ---- fragments + MFMA ----
        f16x8 fah[4], fal[4];
        #pragma unroll
        for (int mf = 0; mf < 4; ++mf) {
            fah[mf] = *reinterpret_cast<const f16x8*>(smem + (mf * 16 + l15) * 80 + g * 16);
            fal[mf] = *reinterpret_cast<const f16x8*>(smem + 5120 + (mf * 16 + l15) * 80 + g * 16);
        }
        #pragma unroll
        for (int nf = 0; nf < 4; ++nf) {
            const int s = w * 64 + nf * 16 + l15;
            const f16x8 fbh = *reinterpret_cast<const f16x8*>(smem + 10240 + s * 64 + ((g * 16) ^ rxor));
            const f16x8 fbl = *reinterpret_cast<const f16x8*>(smem + 26624 + s * 64 + ((g * 16) ^ rxor));
            #pragma unroll
            for (int mf = 0; mf < 4; ++mf) {
                acc[mf][nf] = __builtin_amdgcn_mfma_f32_16x16x32_f16(fah[mf], fbh, acc[mf][nf], 0, 0, 0);
                acc[mf][nf] = __builtin_amdgcn_mfma_f32_16x16x32_f16(fah[mf], fbl, acc[mf][nf], 0, 0, 0);
                acc[mf][nf] = __builtin_amdgcn_mfma_f32_16x16x32_f16(fal[mf], fbh, acc[mf][nf], 0, 0, 0);
            }
        }
        __syncthreads();
    }

    // ---- masked softmax over s ----
    int mv[2][4][4];
    #pragma unroll
    for (int h2 = 0; h2 < 2; ++h2)
        #pragma unroll
        for (int r = 0; r < 4; ++r)
            #pragma unroll
            for (int nf = 0; nf < 4; ++nf)
                mv[h2][r][nf] = mask[(h2 * 16 + g * 4 + r) * Sn + w * 64 + nf * 16 + l15];

    float* redm = reinterpret_cast<float*>(smem + 34816);
    float* reds = reinterpret_cast<float*>(smem + 35840);

    float mx[4][4], sm[4][4];
    #pragma unroll
    for (int mf = 0; mf < 4; ++mf)
        #pragma unroll
        for (int r = 0; r < 4; ++r) {
            float m = -3.0e38f;
            #pragma unroll
            for (int nf = 0; nf < 4; ++nf)
                if (!mv[mf & 1][r][nf]) m = fmaxf(m, acc[mf][nf][r]);
            m = fmaxf(m, __shfl_xor(m, 1, 64));
            m = fmaxf(m, __shfl_xor(m, 2, 64));
            m = fmaxf(m, __shfl_xor(m, 4, 64));
            m = fmaxf(m, __shfl_xor(m, 8, 64));
            mx[mf][r] = m;
        }
    if (l15 == 0) {
        #pragma unroll
        for (int mf = 0; mf < 4; ++mf)
            #pragma unroll
            for (int r = 0; r < 4; ++r)
                redm[w * 64 + mf * 16 + g * 4 + r] = mx[mf][r];
    }
    __syncthreads();
    #pragma unroll
    for (int mf = 0; mf < 4; ++mf)
        #pragma unroll
        for (int r = 0; r < 4; ++r) {
            const int q = mf * 16 + g * 4 + r;
            const float gm = fmaxf(fmaxf(redm[q], redm[64 + q]), fmaxf(redm[128 + q], redm[192 + q]));
            float ssum = 0.f;
            #pragma unroll
            for (int nf = 0; nf < 4; ++nf) {
                const float p = mv[mf & 1][r][nf] ? 0.f : __expf(acc[mf][nf][r] - gm);
                acc[mf][nf][r] = p;
                ssum += p;
            }
            ssum += __shfl_xor(ssum, 1, 64);
            ssum += __shfl_xor(ssum, 2, 64);
            ssum += __shfl_xor(ssum, 4, 64);
            ssum += __shfl_xor(ssum, 8, 64);
            sm[mf][r] = ssum;
        }
    if (l15 == 0) {
        #pragma unroll
        for (int mf = 0; mf < 4; ++mf)
            #pragma unroll
            for (int r = 0; r < 4; ++r)
                reds[w * 64 + mf * 16 + g * 4 + r] = sm[mf][r];
    }
    __syncthreads();
    #pragma unroll
    for (int mf = 0; mf < 4; ++mf)
        #pragma unroll
        for (int r = 0; r < 4; ++r) {
            const int q = mf * 16 + g * 4 + r;
            const float inv = 1.0f / (reds[q] + reds[64 + q] + reds[128 + q] + reds[192 + q]);
            #pragma unroll
            for (int nf = 0; nf < 4; ++nf)
                acc[mf][nf][r] *= inv;
        }

    // ---- outputs: out1 (P^T fp32) + Ph (P fp16 [q][s]) via LDS, 2 s-halves ----
    float* Pl = reinterpret_cast<float*>(smem);
    float* O1 = out1 + (size_t)b * Sn * Qn + q0;
    f16* PhB = Ph + ((size_t)b * Qn + q0) * Sn;
    #pragma unroll
    for (int hf = 0; hf < 2; ++hf) {
        __syncthreads();
        if ((w >> 1) == hf) {
            #pragma unroll
            for (int mf = 0; mf < 4; ++mf)
                #pragma unroll
                for (int nf = 0; nf < 4; ++nf)
                    *reinterpret_cast<f32x4*>(
                        &Pl[((w & 1) * 64 + nf * 16 + l15) * 68 + mf * 16 + g * 4]) = acc[mf][nf];
        }
        __syncthreads();
        #pragma unroll
        for (int j = 0; j < 8; ++j) {
            const int sr = (tid >> 4) + j * 16;
            const int u  = (tid & 15) * 4;
            const f32x4 v = *reinterpret_cast<const f32x4*>(&Pl[sr * 68 + u]);
            *reinterpret_cast<f32x4*>(&O1[(size_t)(hf * 128 + sr) * Qn + u]) = v;
        }
        #pragma unroll
        for (int j = 0; j < 16; ++j) {
            const int colU = l15 + 16 * (j & 3);
            const int q    = (w * 4 + g) + 16 * (j >> 2);
            const float p0 = Pl[(2 * colU) * 68 + q];
            const float p1 = Pl[(2 * colU + 1) * 68 + q];
            f16x2 hh; hh[0] = (f16)p0; hh[1] = (f16)p1;
            *reinterpret_cast<f16x2*>(&PhB[(size_t)q * Sn + hf * 128 + 2 * colU]) = hh;
        }
    }
}

// ---------------------------------------------------------------------------
// K3: out0[b][i][q] = sum_s srcT[b][i][s] * P[b][q][s]   (2-term split MFMA)
// all three tiles via source-swizzled global_load_lds (conflict-free reads)
// block 256 (4 waves 2x2), tile 128i x 128q, K=Sn step 32
// ---------------------------------------------------------------------------
__global__ __launch_bounds__(256) void k_wc(const f16* __restrict__ is_h,
                                            const f16* __restrict__ is_l,
                                            const f16* __restrict__ Ph,
                                            float* __restrict__ out0) {
    // Ah [128][32] @0 (8192), Al @8192, Bh [128][32] @16384
    __shared__ alignas(16) char smem[24576];
    const int tid = threadIdx.x;
    const int w = tid >> 6, lane = tid & 63, g = lane >> 4, l15 = lane & 15;
    const int wi = w >> 1, wq = w & 1;
    const int rxor = ((l15 >> 1) & 3) << 4;

    const int lin = (blockIdx.z * 8 + blockIdx.y) * 18 + blockIdx.x;
    const int swz = (lin & 7) * 576 + (lin >> 3);
    const int b = swz / 144;
    const int rr = swz - b * 144;
    const int it = rr / 18, qt = rr - it * 18;
    const int i0 = it * 128, q0 = qt * 128;

    const f16* AhG = is_h + ((size_t)b * IDF + i0) * Sn;
    const f16* AlG = is_l + ((size_t)b * IDF + i0) * Sn;
    const f16* BG  = Ph  + ((size_t)b * Qn + q0) * Sn;

    f32x4 acc[4][4];
    {
        f32x4 z = {0.f, 0.f, 0.f, 0.f};
        #pragma unroll
        for (int mf = 0; mf < 4; ++mf)
            #pragma unroll
            for (int nf = 0; nf < 4; ++nf)
                acc[mf][nf] = z;
    }

    for (int kk = 0; kk < Sn; kk += 32) {
        #pragma unroll
        for (int t2 = 0; t2 < 2; ++t2) {
            const int byt = (w * 2 + t2) * 1024 + lane * 16;
            const int rw = byt >> 6;
            const int so = ((((byt >> 4) & 3) ^ ((rw >> 1) & 3)) << 3);   // f16 units
            const size_t go = (size_t)rw * Sn + kk + so;
            gll16(AhG + go, smem + (w * 2 + t2) * 1024);
            gll16(AlG + go, smem + 8192 + (w * 2 + t2) * 1024);
            gll16(BG  + go, smem + 16384 + (w * 2 + t2) * 1024);
        }
        __syncthreads();
        f16x8 fah[4], fal[4];
        #pragma unroll
        for (int mf = 0; mf < 4; ++mf) {
            const int row = wi * 64 + mf * 16 + l15;
            fah[mf] = *reinterpret_cast<const f16x8*>(smem + row * 64 + ((g * 16) ^ rxor));
            fal[mf] = *reinterpret_cast<const f16x8*>(smem + 8192 + row * 64 + ((g * 16) ^ rxor));
        }
        #pragma unroll
        for (int nf = 0; nf < 4; ++nf) {
            const int row = wq * 64 + nf * 16 + l15;
            const f16x8 fbh = *reinterpret_cast<const f16x8*>(smem + 16384 + row * 64 + ((g * 16) ^ rxor));
            #pragma unroll
            for (int mf = 0; mf < 4; ++mf) {
                acc[mf][nf] = __builtin_amdgcn_mfma_f32_16x16x32_f16(fah[mf], fbh, acc[mf][nf], 0, 0, 0);
                acc[mf][nf] = __builtin_amdgcn_mfma_f32_16x16x32_f16(fal[mf], fbh, acc[mf][nf], 0, 0, 0);
            }
        }
        __syncthreads();
    }
    float* O = out0 + ((size_t)b * IDF + i0 + wi * 64) * Qn + q0 + wq * 64;
    #pragma unroll
    for (int mf = 0; mf < 4; ++mf)
        #pragma unroll
        for (int nf = 0; nf < 4; ++nf)
            #pragma unroll
            for (int r = 0; r < 4; ++r)
                O[(size_t)(mf * 16 + g * 4 + r) * Qn + nf * 16 + l15] = acc[mf][nf][r];
}

extern "C" void kernel_launch(void* const* d_in, const int* in_sizes, int n_in,
                              void* d_out, int out_size, void* d_ws, size_t ws_size,
                              hipStream_t stream) {
    const float* inp  = (const float*)d_in[0];   // [B, IDF, 48, 48]
    const float* ctx  = (const float*)d_in[1];   // [B, CDF, S]
    const int*   mask = (const int*)  d_in[2];   // [B, S]
    const float* W    = (const float*)d_in[3];   // [IDF, CDF]
    float* out0 = (float*)d_out;                             // weightedContext
    float* out1 = out0 + (size_t)Bn * IDF * Qn;              // attn_out = P^T

    char* ws = (char*)d_ws;
    const size_t SZ = (size_t)Bn * Sn * IDF * sizeof(f16);   // 16 MiB
    f16* si_h = (f16*)(ws);
    f16* si_l = (f16*)(ws + SZ);
    f16* is_h = (f16*)(ws + 2 * SZ);
    f16* is_l = (f16*)(ws + 3 * SZ);
    f16* Ph   = (f16*)(ws + 4 * SZ);                         // [B][Q][S] fp16
    // W hi/lo alias the Ph region (dead until k_attn; k_srcT completes first)
    f16* Wh   = (f16*)(ws + 4 * SZ);
    f16* Wl   = Wh + (size_t)IDF * CDF;

    hipLaunchKernelGGL(k_wsplit, dim3(IDF * CDF / 1024), dim3(256), 0, stream, W, Wh, Wl);
    hipLaunchKernelGGL(k_srcT, dim3(Sn / 128, IDF / 128, Bn), dim3(256), 0, stream,
                       Wh, Wl, ctx, si_h, si_l, is_h, is_l);
    hipLaunchKernelGGL(k_attn, dim3(Qn / 64, Bn), dim3(256), 0, stream,
                       inp, si_h, si_l, mask, out1, Ph);
    hipLaunchKernelGGL(k_wc, dim3(Qn / 128, IDF / 128, Bn), dim3(256), 0, stream,
                       is_h, is_l, Ph, out0);
}

// Round 5
// 400.902 us; speedup vs baseline: 1.5634x; 1.1475x over previous
//
#include <hip/hip_runtime.h>

#define Bn  32
#define IDF 1024
#define CDF 1024
#define Qn  2304
#define Sn  256

typedef _Float16 f16;
typedef _Float16 f16x2 __attribute__((ext_vector_type(2)));
typedef _Float16 f16x4 __attribute__((ext_vector_type(4)));
typedef _Float16 f16x8 __attribute__((ext_vector_type(8)));
typedef float    f32x4 __attribute__((ext_vector_type(4)));

// async global->LDS, 16B per lane; dest = wave-uniform base + lane*16
__device__ __forceinline__ void gll16(const void* g, void* l) {
    __builtin_amdgcn_global_load_lds((const __attribute__((address_space(1))) void*)g,
                                     (__attribute__((address_space(3))) void*)l, 16, 0, 0);
}

// split fp32 into fp16 hi + fp16 lo (x ~= hi + lo, error ~2^-23*|x|)
__device__ __forceinline__ void fsplit(float x, f16& hi, f16& lo) {
    hi = (f16)x;
    lo = (f16)(x - (float)hi);
}

// ---------------------------------------------------------------------------
// K0: split W into fp16 hi/lo (runs once, ~4 MB traffic)
// ---------------------------------------------------------------------------
__global__ __launch_bounds__(256) void k_wsplit(const float* __restrict__ W,
                                                f16* __restrict__ Wh, f16* __restrict__ Wl) {
    const int idx = (blockIdx.x * 256 + threadIdx.x) * 4;
    const float4 v = *reinterpret_cast<const float4*>(&W[idx]);
    f16x4 h4, l4;
    f16 h, l;
    fsplit(v.x, h, l); h4[0] = h; l4[0] = l;
    fsplit(v.y, h, l); h4[1] = h; l4[1] = l;
    fsplit(v.z, h, l); h4[2] = h; l4[2] = l;
    fsplit(v.w, h, l); h4[3] = h; l4[3] = l;
    *reinterpret_cast<f16x4*>(&Wh[idx]) = h4;
    *reinterpret_cast<f16x4*>(&Wl[idx]) = l4;
}

// ---------------------------------------------------------------------------
// K1: srcT[b][i][s] = sum_c W[i][c] * ctx[b][c][s]  -- 3-term split-fp16 MFMA
// 4x1 wave grid: wave w owns i rows [w*32, w*32+32) -> W slice is WAVE-PRIVATE,
// single-buffered, re-staged via gll16 after lgkmcnt(0) (no barrier for W).
// ctx: fp32 prefetch-next -> split -> XOR-swizzled dbuf LDS. 1 barrier/iter.
// grid (Sn/128, IDF/128, Bn), block 256, tile 128i x 128s
// ---------------------------------------------------------------------------
__global__ __launch_bounds__(256) void k_srcT(const f16* __restrict__ Wh,
                                              const f16* __restrict__ Wl,
                                              const float* __restrict__ ctx,
                                              f16* __restrict__ si_h, f16* __restrict__ si_l,
                                              f16* __restrict__ is_h, f16* __restrict__ is_l) {
    // LDS: Wh [128][64B] @0 (8192), Wl @8192 (8192)  (wave-private slices)
    //      ctx dbuf: buf x @16384+x*16384 { Ch (8192), Cl (8192) }  -> 49152 total
    __shared__ alignas(16) char smem[49152];
    const int tid = threadIdx.x;
    const int w = tid >> 6, lane = tid & 63, g = lane >> 4, l15 = lane & 15;
    const int rxor = ((l15 >> 1) & 3) << 4;

    // bijective XCD swizzle over 512 blocks
    const int lin = (blockIdx.z * 8 + blockIdx.y) * 2 + blockIdx.x;
    const int swz = (lin & 7) * 64 + (lin >> 3);
    const int b = swz >> 4, rr = swz & 15;
    const int i0 = (rr >> 1) * 128, s0 = (rr & 1) * 128;

    const float* Cp = ctx + (size_t)b * CDF * Sn + s0;
    const int sl = tid & 127, ch = tid >> 7;     // ctx staging: column s, c-chunk
    const int swzw = ((sl >> 1) & 3) << 4;       // ctx write-side XOR (row = sl)

    f32x4 acc[2][8];
    {
        f32x4 z = {0.f, 0.f, 0.f, 0.f};
        #pragma unroll
        for (int mf = 0; mf < 2; ++mf)
            #pragma unroll
            for (int nf = 0; nf < 8; ++nf)
                acc[mf][nf] = z;
    }

    // ---- prologue: W tile 0 (wave-private slice) + ctx tile 0 -> buf0 ----
    #pragma unroll
    for (int part = 0; part < 2; ++part) {
        const int byt = w * 2048 + part * 1024 + lane * 16;
        const int rw = byt >> 6;
        const int co = ((((byt >> 4) & 3) ^ ((rw >> 1) & 3)) << 3);
        const size_t go = (size_t)(i0 + rw) * CDF + co;
        gll16(Wh + go, smem + w * 2048 + part * 1024);
        gll16(Wl + go, smem + 8192 + w * 2048 + part * 1024);
    }
    {
        float cv[16];
        #pragma unroll
        for (int j = 0; j < 16; ++j)
            cv[j] = Cp[(size_t)(ch * 16 + j) * Sn + sl];
        f16x8 h0, h1, l0, l1;
        #pragma unroll
        for (int j = 0; j < 8; ++j) { f16 h, l; fsplit(cv[j], h, l); h0[j] = h; l0[j] = l; }
        #pragma unroll
        for (int j = 0; j < 8; ++j) { f16 h, l; fsplit(cv[8 + j], h, l); h1[j] = h; l1[j] = l; }
        char* cb = smem + 16384 + sl * 64;
        *reinterpret_cast<f16x8*>(cb + (((ch * 32) + 0) ^ swzw))        = h0;
        *reinterpret_cast<f16x8*>(cb + (((ch * 32) + 16) ^ swzw))       = h1;
        *reinterpret_cast<f16x8*>(cb + 8192 + (((ch * 32) + 0) ^ swzw)) = l0;
        *reinterpret_cast<f16x8*>(cb + 8192 + (((ch * 32) + 16) ^ swzw))= l1;
    }
    __syncthreads();

    for (int t = 0; t < 32; ++t) {
        const int kk = t * 32;
        // ---- W frag ds_reads (must complete before re-staging same slice) ----
        f16x8 fwh[2], fwl[2];
        #pragma unroll
        for (int mf = 0; mf < 2; ++mf) {
            const int row = w * 32 + mf * 16 + l15;
            fwh[mf] = *reinterpret_cast<const f16x8*>(smem + row * 64 + ((g * 16) ^ rxor));
            fwl[mf] = *reinterpret_cast<const f16x8*>(smem + 8192 + row * 64 + ((g * 16) ^ rxor));
        }
        asm volatile("s_waitcnt lgkmcnt(0)" ::: "memory");
        __builtin_amdgcn_sched_barrier(0);
        float cv[16];
        if (t < 31) {
            // W(t+1) gll16 into own slice (async, lands under MFMA)
            #pragma unroll
            for (int part = 0; part < 2; ++part) {
                const int byt = w * 2048 + part * 1024 + lane * 16;
                const int rw = byt >> 6;
                const int co = ((((byt >> 4) & 3) ^ ((rw >> 1) & 3)) << 3);
                const size_t go = (size_t)(i0 + rw) * CDF + kk + 32 + co;
                gll16(Wh + go, smem + w * 2048 + part * 1024);
                gll16(Wl + go, smem + 8192 + w * 2048 + part * 1024);
            }
            // ctx(t+1) fp32 prefetch (consumed after MFMA)
            #pragma unroll
            for (int j = 0; j < 16; ++j)
                cv[j] = Cp[(size_t)(kk + 32 + ch * 16 + j) * Sn + sl];
        }
        // ---- MFMA (3-term), per-nf ctx frag reads from buf[t&1] ----
        const char* cbuf = smem + 16384 + (t & 1) * 16384;
        __builtin_amdgcn_s_setprio(1);
        #pragma unroll
        for (int nf = 0; nf < 8; ++nf) {
            const int srow = nf * 16 + l15;
            const f16x8 fch = *reinterpret_cast<const f16x8*>(cbuf + srow * 64 + ((g * 16) ^ rxor));
            const f16x8 fcl = *reinterpret_cast<const f16x8*>(cbuf + 8192 + srow * 64 + ((g * 16) ^ rxor));
            #pragma unroll
            for (int mf = 0; mf < 2; ++mf) {
                acc[mf][nf] = __builtin_amdgcn_mfma_f32_16x16x32_f16(fwh[mf], fch, acc[mf][nf], 0, 0, 0);
                acc[mf][nf] = __builtin_amdgcn_mfma_f32_16x16x32_f16(fwh[mf], fcl, acc[mf][nf], 0, 0, 0);
                acc[mf][nf] = __builtin_amdgcn_mfma_f32_16x16x32_f16(fwl[mf], fch, acc[mf][nf], 0, 0, 0);
            }
        }
        __builtin_amdgcn_s_setprio(0);
        // ---- split + write ctx(t+1) into other buffer ----
        if (t < 31) {
            f16x8 h0, h1, l0, l1;
            #pragma unroll
            for (int j = 0; j < 8; ++j) { f16 h, l; fsplit(cv[j], h, l); h0[j] = h; l0[j] = l; }
            #pragma unroll
            for (int j = 0; j < 8; ++j) { f16 h, l; fsplit(cv[8 + j], h, l); h1[j] = h; l1[j] = l; }
            char* cb = smem + 16384 + ((t + 1) & 1) * 16384 + sl * 64;
            *reinterpret_cast<f16x8*>(cb + (((ch * 32) + 0) ^ swzw))        = h0;
            *reinterpret_cast<f16x8*>(cb + (((ch * 32) + 16) ^ swzw))       = h1;
            *reinterpret_cast<f16x8*>(cb + 8192 + (((ch * 32) + 0) ^ swzw)) = l0;
            *reinterpret_cast<f16x8*>(cb + 8192 + (((ch * 32) + 16) ^ swzw))= l1;
        }
        __syncthreads();
    }

    // ---- epilogue: split once, store both layouts ----
    #pragma unroll
    for (int mf = 0; mf < 2; ++mf)
        #pragma unroll
        for (int nf = 0; nf < 8; ++nf) {
            f16x4 h4, l4;
            #pragma unroll
            for (int r = 0; r < 4; ++r) { f16 h, l; fsplit(acc[mf][nf][r], h, l); h4[r] = h; l4[r] = l; }
            const int s  = s0 + nf * 16 + l15;
            const int ib = i0 + w * 32 + mf * 16 + g * 4;
            const size_t so = ((size_t)b * Sn + s) * IDF + ib;
            *reinterpret_cast<f16x4*>(&si_h[so]) = h4;
            *reinterpret_cast<f16x4*>(&si_l[so]) = l4;
            #pragma unroll
            for (int r = 0; r < 4; ++r) {
                const size_t io = ((size_t)b * IDF + ib + r) * Sn + s;
                is_h[io] = h4[r];
                is_l[io] = l4[r];
            }
        }
}

// ---------------------------------------------------------------------------
// K2: logits via 3-term split-fp16 MFMA + fused masked softmax
// Wave w consumes ONLY B rows [w*64, w*64+64) -> B slice is WAVE-PRIVATE,
// single-buffered, re-staged via gll16 after lgkmcnt(0) (no barrier for B).
// A (inp): fp32 prefetch-next -> split -> XOR-swizzled dbuf LDS. 1 barrier/iter.
// grid (Qn/64, Bn), block 256 (4 waves 1x4), tile 64q x 256s
// ---------------------------------------------------------------------------
__global__ __launch_bounds__(256) void k_attn(const float* __restrict__ inp,
                                              const f16* __restrict__ si_h,
                                              const f16* __restrict__ si_l,
                                              const int* __restrict__ mask,
                                              float* __restrict__ out1,
                                              f16* __restrict__ Ph) {
    // LDS: A dbuf: buf x @x*8192 { Ah (4096), Al (4096) } -> 0..16384
    //      Bh [256][64B] @16384 (16384), Bl @32768 (16384) -> 49152 total
    //      epilogue union: Pl f32 [128][68] @0 (34816), redm @34816, reds @35840
    __shared__ alignas(16) char smem[49152];
    const int tid = threadIdx.x;
    const int w = tid >> 6, lane = tid & 63, g = lane >> 4, l15 = lane & 15;
    const int rxor = ((l15 >> 1) & 3) << 4;
    const int awz  = ((lane >> 1) & 3) << 4;     // A write-side XOR (row = lane)

    const int lin = blockIdx.y * 36 + blockIdx.x;
    const int swzb = (lin & 7) * 144 + (lin >> 3);
    const int b = swzb / 36, qt = swzb - b * 36;
    const int q0 = qt * 64;

    const float* Ap = inp + (size_t)b * IDF * Qn + q0;
    const f16* BhG = si_h + (size_t)b * Sn * IDF;
    const f16* BlG = si_l + (size_t)b * Sn * IDF;

    f32x4 acc[4][4];
    {
        f32x4 z = {0.f, 0.f, 0.f, 0.f};
        #pragma unroll
        for (int mf = 0; mf < 4; ++mf)
            #pragma unroll
            for (int nf = 0; nf < 4; ++nf)
                acc[mf][nf] = z;
    }

    // ---- prologue: B tile 0 (wave slice) + A tile 0 -> buf0 ----
    #pragma unroll
    for (int it = 0; it < 4; ++it) {
        const int byt = w * 4096 + it * 1024 + lane * 16;
        const int s = byt >> 6;
        const int ko = ((((byt >> 4) & 3) ^ ((s >> 1) & 3)) << 3);
        const size_t go = (size_t)s * IDF + ko;
        gll16(BhG + go, smem + 16384 + w * 4096 + it * 1024);
        gll16(BlG + go, smem + 32768 + w * 4096 + it * 1024);
    }
    {
        float av[8];
        #pragma unroll
        for (int j = 0; j < 8; ++j)
            av[j] = Ap[(size_t)(w * 8 + j) * Qn + lane];
        f16x8 ah, al;
        #pragma unroll
        for (int j = 0; j < 8; ++j) { f16 h, lo; fsplit(av[j], h, lo); ah[j] = h; al[j] = lo; }
        *reinterpret_cast<f16x8*>(smem + lane * 64 + ((w * 16) ^ awz)) = ah;
        *reinterpret_cast<f16x8*>(smem + 4096 + lane * 64 + ((w * 16) ^ awz)) = al;
    }
    __syncthreads();

    for (int t = 0; t < 32; ++t) {
        const int kk = t * 32;
        // ---- B frag ds_reads (must complete before re-staging same slice) ----
        f16x8 fbh[4], fbl[4];
        #pragma unroll
        for (int nf = 0; nf < 4; ++nf) {
            const int row = w * 64 + nf * 16 + l15;
            fbh[nf] = *reinterpret_cast<const f16x8*>(smem + 16384 + row * 64 + ((g * 16) ^ rxor));
            fbl[nf] = *reinterpret_cast<const f16x8*>(smem + 32768 + row * 64 + ((g * 16) ^ rxor));
        }
        asm volatile("s_waitcnt lgkmcnt(0)" ::: "memory");
        __builtin_amdgcn_sched_barrier(0);
        float av[8];
        if (t < 31) {
            // B(t+1) gll16 into own slice (async, lands under MFMA)
            #pragma unroll
            for (int it = 0; it < 4; ++it) {
                const int byt = w * 4096 + it * 1024 + lane * 16;
                const int s = byt >> 6;
                const int ko = ((((byt >> 4) & 3) ^ ((s >> 1) & 3)) << 3);
                const size_t go = (size_t)s * IDF + kk + 32 + ko;
                gll16(BhG + go, smem + 16384 + w * 4096 + it * 1024);
                gll16(BlG + go, smem + 32768 + w * 4096 + it * 1024);
            }
            // A(t+1) fp32 prefetch
            #pragma unroll
            for (int j = 0; j < 8; ++j)
                av[j] = Ap[(size_t)(kk + 32 + w * 8 + j) * Qn + lane];
        }
        // ---- MFMA (3-term), per-mf A frag reads from buf[t&1] ----
        const char* ab = smem + (t & 1) * 8192;
        __builtin_amdgcn_s_setprio(1);
        #pragma unroll
        for (int mf = 0; mf < 4; ++mf) {
            const f16x8 fah = *reinterpret_cast<const f16x8*>(ab + (mf * 16 + l15) * 64 + ((g * 16) ^ rxor));
            const f16x8 fal = *reinterpret_cast<const f16x8*>(ab + 4096 + (mf * 16 + l15) * 64 + ((g * 16) ^ rxor));
            #pragma unroll
            for (int nf = 0; nf < 4; ++nf) {
                acc[mf][nf] = __builtin_amdgcn_mfma_f32_16x16x32_f16(fah, fbh[nf], acc[mf][nf], 0, 0, 0);
                acc[mf][nf] = __builtin_amdgcn_mfma_f32_16x16x32_f16(fah, fbl[nf], acc[mf][nf], 0, 0, 0);
                acc[mf][nf] = __builtin_amdgcn_mfma_f32_16x16x32_f16(fal, fbh[nf], acc[mf][nf], 0, 0, 0);
            }
        }
        __builtin_amdgcn_s_setprio(0);
        // ---- split + write A(t+1) into other buffer ----
        if (t < 31) {
            f16x8 ah, al;
            #pragma unroll
            for (int j = 0; j < 8; ++j) { f16 h, lo; fsplit(av[j], h, lo); ah[j] = h; al[j] = lo; }
            char* wb = smem + ((t + 1) & 1) * 8192;
            *reinterpret_cast<f16x8*>(wb + lane * 64 + ((w * 16) ^ awz)) = ah;
            *reinterpret_cast<f16x8*>(wb + 4096 + lane * 64 + ((w * 16) ^ awz)) = al;
        }
        __syncthreads();
    }

    // ---- masked softmax over s ----
    int mv[2][4][4];
    #pragma unroll
    for (int h2 = 0; h2 < 2; ++h2)
        #pragma unroll
        for (int r = 0; r < 4; ++r)
            #pragma unroll
            for (int nf = 0; nf < 4; ++nf)
                mv[h2][r][nf] = mask[(h2 * 16 + g * 4 + r) * Sn + w * 64 + nf * 16 + l15];

    float* redm = reinterpret_cast<float*>(smem + 34816);
    float* reds = reinterpret_cast<float*>(smem + 35840);

    float mx[4][4], sm[4][4];
    #pragma unroll
    for (int mf = 0; mf < 4; ++mf)
        #pragma unroll
        for (int r = 0; r < 4; ++r) {
            float m = -3.0e38f;
            #pragma unroll
            for (int nf = 0; nf < 4; ++nf)
                if (!mv[mf & 1][r][nf]) m = fmaxf(m, acc[mf][nf][r]);
            m = fmaxf(m, __shfl_xor(m, 1, 64));
            m = fmaxf(m, __shfl_xor(m, 2, 64));
            m = fmaxf(m, __shfl_xor(m, 4, 64));
            m = fmaxf(m, __shfl_xor(m, 8, 64));
            mx[mf][r] = m;
        }
    if (l15 == 0) {
        #pragma unroll
        for (int mf = 0; mf < 4; ++mf)
            #pragma unroll
            for (int r = 0; r < 4; ++r)
                redm[w * 64 + mf * 16 + g * 4 + r] = mx[mf][r];
    }
    __syncthreads();
    #pragma unroll
    for (int mf = 0; mf < 4; ++mf)
        #pragma unroll
        for (int r = 0; r < 4; ++r) {
            const int q = mf * 16 + g * 4 + r;
            const float gm = fmaxf(fmaxf(redm[q], redm[64 + q]), fmaxf(redm[128 + q], redm[192 + q]));
            float ssum = 0.f;
            #pragma unroll
            for (int nf = 0; nf < 4; ++nf) {
                const float p = mv[mf & 1][r][nf] ? 0.f : __expf(acc[mf][nf][r] - gm);
                acc[mf][nf][r] = p;
                ssum += p;
            }
            ssum += __shfl_xor(ssum, 1, 64);
            ssum += __shfl_xor(ssum, 2, 64);
            ssum += __shfl_xor(ssum, 4, 64);
            ssum += __shfl_xor(ssum, 8, 64);
            sm[mf][r] = ssum;
        }
    if (l15 == 0) {
        #pragma unroll
        for (int mf = 0; mf < 4; ++mf)
            #pragma unroll
            for (int r = 0; r < 4; ++r)
                reds[w * 64 + mf * 16 + g * 4 + r] = sm[mf][r];
    }
    __syncthreads();
    #pragma unroll
    for (int mf = 0; mf < 4; ++mf)
        #pragma unroll
        for (int r = 0; r < 4; ++r) {
            const int q = mf * 16 + g * 4 + r;
            const float inv = 1.0f / (reds[q] + reds[64 + q] + reds[128 + q] + reds[192 + q]);
            #pragma unroll
            for (int nf = 0; nf < 4; ++nf)
                acc[mf][nf][r] *= inv;
        }

    // ---- outputs: out1 (P^T fp32) + Ph (P fp16 [q][s]) via LDS, 2 s-halves ----
    float* Pl = reinterpret_cast<float*>(smem);
    float* O1 = out1 + (size_t)b * Sn * Qn + q0;
    f16* PhB = Ph + ((size_t)b * Qn + q0) * Sn;
    #pragma unroll
    for (int hf = 0; hf < 2; ++hf) {
        __syncthreads();
        if ((w >> 1) == hf) {
            #pragma unroll
            for (int mf = 0; mf < 4; ++mf)
                #pragma unroll
                for (int nf = 0; nf < 4; ++nf)
                    *reinterpret_cast<f32x4*>(
                        &Pl[((w & 1) * 64 + nf * 16 + l15) * 68 + mf * 16 + g * 4]) = acc[mf][nf];
        }
        __syncthreads();
        #pragma unroll
        for (int j = 0; j < 8; ++j) {
            const int sr = (tid >> 4) + j * 16;
            const int u  = (tid & 15) * 4;
            const f32x4 v = *reinterpret_cast<const f32x4*>(&Pl[sr * 68 + u]);
            *reinterpret_cast<f32x4*>(&O1[(size_t)(hf * 128 + sr) * Qn + u]) = v;
        }
        #pragma unroll
        for (int j = 0; j < 16; ++j) {
            const int colU = l15 + 16 * (j & 3);
            const int q    = (w * 4 + g) + 16 * (j >> 2);
            const float p0 = Pl[(2 * colU) * 68 + q];
            const float p1 = Pl[(2 * colU + 1) * 68 + q];
            f16x2 hh; hh[0] = (f16)p0; hh[1] = (f16)p1;
            *reinterpret_cast<f16x2*>(&PhB[(size_t)q * Sn + hf * 128 + 2 * colU]) = hh;
        }
    }
}

// ---------------------------------------------------------------------------
// K3: out0[b][i][q] = sum_s srcT[b][i][s] * P[b][q][s]   (2-term split MFMA)
// prefetch-next double buffer: gll16(t+1) -> other buffer issued BEFORE the
// ds_reads of buffer t (no hazard, no wait), 1 barrier/iter.
// block 256 (4 waves 2x2), tile 128i x 128q, K=Sn step 32
// ---------------------------------------------------------------------------
__global__ __launch_bounds__(256) void k_wc(const f16* __restrict__ is_h,
                                            const f16* __restrict__ is_l,
                                            const f16* __restrict__ Ph,
                                            float* __restrict__ out0) {
    // dbuf: buf x @x*24576 { Ah (8192), Al (8192), Bh (8192) } -> 49152
    __shared__ alignas(16) char smem[49152];
    const int tid = threadIdx.x;
    const int w = tid >> 6, lane = tid & 63, g = lane >> 4, l15 = lane & 15;
    const int wi = w >> 1, wq = w & 1;
    const int rxor = ((l15 >> 1) & 3) << 4;

    const int lin = (blockIdx.z * 8 + blockIdx.y) * 18 + blockIdx.x;
    const int swz = (lin & 7) * 576 + (lin >> 3);
    const int b = swz / 144;
    const int rr = swz - b * 144;
    const int it = rr / 18, qt = rr - it * 18;
    const int i0 = it * 128, q0 = qt * 128;

    const f16* AhG = is_h + ((size_t)b * IDF + i0) * Sn;
    const f16* AlG = is_l + ((size_t)b * IDF + i0) * Sn;
    const f16* BG  = Ph  + ((size_t)b * Qn + q0) * Sn;

    f32x4 acc[4][4];
    {
        f32x4 z = {0.f, 0.f, 0.f, 0.f};
        #pragma unroll
        for (int mf = 0; mf < 4; ++mf)
            #pragma unroll
            for (int nf = 0; nf < 4; ++nf)
                acc[mf][nf] = z;
    }

    // prologue: stage tile 0 -> buf0
    #pragma unroll
    for (int t2 = 0; t2 < 2; ++t2) {
        const int byt = (w * 2 + t2) * 1024 + lane * 16;
        const int rw = byt >> 6;
        const int so = ((((byt >> 4) & 3) ^ ((rw >> 1) & 3)) << 3);
        const size_t go = (size_t)rw * Sn + so;
        gll16(AhG + go, smem + (w * 2 + t2) * 1024);
        gll16(AlG + go, smem + 8192 + (w * 2 + t2) * 1024);
        gll16(BG  + go, smem + 16384 + (w * 2 + t2) * 1024);
    }
    __syncthreads();

    for (int t = 0; t < 8; ++t) {
        const int kk = t * 32;
        if (t < 7) {   // stage t+1 into other buffer (no wait needed)
            #pragma unroll
            for (int t2 = 0; t2 < 2; ++t2) {
                const int byt = (w * 2 + t2) * 1024 + lane * 16;
                const int rw = byt >> 6;
                const int so = ((((byt >> 4) & 3) ^ ((rw >> 1) & 3)) << 3);
                const size_t go = (size_t)rw * Sn + kk + 32 + so;
                char* dst = smem + ((t + 1) & 1) * 24576 + (w * 2 + t2) * 1024;
                gll16(AhG + go, dst);
                gll16(AlG + go, dst + 8192);
                gll16(BG  + go, dst + 16384);
            }
        }
        const char* buf = smem + (t & 1) * 24576;
        f16x8 fah[4], fal[4];
        #pragma unroll
        for (int mf = 0; mf < 4; ++mf) {
            const int row = wi * 64 + mf * 16 + l15;
            fah[mf] = *reinterpret_cast<const f16x8*>(buf + row * 64 + ((g * 16) ^ rxor));
            fal[mf] = *reinterpret_cast<const f16x8*>(buf + 8192 + row * 64 + ((g * 16) ^ rxor));
        }
        __builtin_amdgcn_s_setprio(1);
        #pragma unroll
        for (int nf = 0; nf < 4; ++nf) {
            const int row = wq * 64 + nf * 16 + l15;
            const f16x8 fbh = *reinterpret_cast<const f16x8*>(buf + 16384 + row * 64 + ((g * 16) ^ rxor));
            #pragma unroll
            for (int mf = 0; mf < 4; ++mf) {
                acc[mf][nf] = __builtin_amdgcn_mfma_f32_16x16x32_f16(fah[mf], fbh, acc[mf][nf], 0, 0, 0);
                acc[mf][nf] = __builtin_amdgcn_mfma_f32_16x16x32_f16(fal[mf], fbh, acc[mf][nf], 0, 0, 0);
            }
        }
        __builtin_amdgcn_s_setprio(0);
        __syncthreads();
    }
    float* O = out0 + ((size_t)b * IDF + i0 + wi * 64) * Qn + q0 + wq * 64;
    #pragma unroll
    for (int mf = 0; mf < 4; ++mf)
        #pragma unroll
        for (int nf = 0; nf < 4; ++nf)
            #pragma unroll
            for (int r = 0; r < 4; ++r)
                O[(size_t)(mf * 16 + g * 4 + r) * Qn + nf * 16 + l15] = acc[mf][nf][r];
}

extern "C" void kernel_launch(void* const* d_in, const int* in_sizes, int n_in,
                              void* d_out, int out_size, void* d_ws, size_t ws_size,
                              hipStream_t stream) {
    const float* inp  = (const float*)d_in[0];   // [B, IDF, 48, 48]
    const float* ctx  = (const float*)d_in[1];   // [B, CDF, S]
    const int*   mask = (const int*)  d_in[2];   // [B, S]
    const float* W    = (const float*)d_in[3];   // [IDF, CDF]
    float* out0 = (float*)d_out;                             // weightedContext
    float* out1 = out0 + (size_t)Bn * IDF * Qn;              // attn_out = P^T

    char* ws = (char*)d_ws;
    const size_t SZ = (size_t)Bn * Sn * IDF * sizeof(f16);   // 16 MiB
    f16* si_h = (f16*)(ws);
    f16* si_l = (f16*)(ws + SZ);
    f16* is_h = (f16*)(ws + 2 * SZ);
    f16* is_l = (f16*)(ws + 3 * SZ);
    f16* Ph   = (f16*)(ws + 4 * SZ);                         // [B][Q][S] fp16
    // W hi/lo alias the Ph region (dead until k_attn; k_srcT completes first)
    f16* Wh   = (f16*)(ws + 4 * SZ);
    f16* Wl   = Wh + (size_t)IDF * CDF;

    hipLaunchKernelGGL(k_wsplit, dim3(IDF * CDF / 1024), dim3(256), 0, stream, W, Wh, Wl);
    hipLaunchKernelGGL(k_srcT, dim3(Sn / 128, IDF / 128, Bn), dim3(256), 0, stream,
                       Wh, Wl, ctx, si_h, si_l, is_h, is_l);
    hipLaunchKernelGGL(k_attn, dim3(Qn / 64, Bn), dim3(256), 0, stream,
                       inp, si_h, si_l, mask, out1, Ph);
    hipLaunchKernelGGL(k_wc, dim3(Qn / 128, IDF / 128, Bn), dim3(256), 0, stream,
                       is_h, is_l, Ph, out0);
}